// Round 9
// baseline (441.049 us; speedup 1.0000x reference)
//
#include <hip/hip_runtime.h>

typedef _Float16 f16;
typedef _Float16 f16x8 __attribute__((ext_vector_type(8)));
typedef _Float16 f16x4 __attribute__((ext_vector_type(4)));
typedef float f32x4 __attribute__((ext_vector_type(4)));
typedef unsigned u32x4 __attribute__((ext_vector_type(4)));

#define NB 32
#define NS 1024
#define NI 128
#define NR 1024
#define NO 128
#define NG 8       // workgroups per chunk (each WG owns 128 columns)
#define NC 32      // chunks
#define WARM 16    // warm-start depth (validated r7/r8)
#define CHUNK 32   // real steps per chunk -> 48 serial steps

#define MFMA16(a,b,c) __builtin_amdgcn_mfma_f32_16x16x32_f16((a),(b),(c),0,0,0)

__device__ inline f16x8 cvt8(const float* p) {
  float4 a = *(const float4*)p, b = *(const float4*)(p + 4);
  f16x8 v;
  v[0]=(f16)a.x; v[1]=(f16)a.y; v[2]=(f16)a.z; v[3]=(f16)a.w;
  v[4]=(f16)b.x; v[5]=(f16)b.y; v[6]=(f16)b.z; v[7]=(f16)b.w;
  return v;
}

// ---------------- kernel 1: W/W_out f16 preconvert + x_proj[t] in MFMA C-frag order ----
__global__ __launch_bounds__(256) void xp_kernel(
    const float* __restrict__ x, const float* __restrict__ Win, f16* __restrict__ xpw,
    const float* __restrict__ W, const float* __restrict__ Wow,
    f16* __restrict__ Wh, f16* __restrict__ Woh)
{
  __shared__ __attribute__((aligned(16))) f16 Xs[4][32][136];  // 34.8 KB
  const int tid = threadIdx.x, lane = tid & 63, wv = tid >> 6;
  const int q = lane >> 4, ln = lane & 15;
  const int t0 = blockIdx.x * 4;

  // ---- merged conv: 65536 threads convert W (1M f32, 4xfloat4 each) + Wow (128K, 2x) ----
  {
    const int base = blockIdx.x * 256 + tid;
#pragma unroll
    for (int k = 0; k < 4; ++k) {
      int i = base + k * 65536;
      float4 v = *(const float4*)(W + (size_t)i * 4);
      f16x4 h; h[0]=(f16)v.x; h[1]=(f16)v.y; h[2]=(f16)v.z; h[3]=(f16)v.w;
      *(f16x4*)&Wh[(size_t)i * 4] = h;
    }
#pragma unroll
    for (int k = 0; k < 2; ++k) {
      int i = base + k * 65536;
      if (i < NO * NR / 4) {
        float4 v = *(const float4*)(Wow + (size_t)i * 4);
        f16x4 h; h[0]=(f16)v.x; h[1]=(f16)v.y; h[2]=(f16)v.z; h[3]=(f16)v.w;
        *(f16x4*)&Woh[(size_t)i * 4] = h;
      }
    }
  }

#pragma unroll
  for (int j = 0; j < 16; ++j) {
    int idx = tid + j*256;
    int tp = idx >> 10, rem = idx & 1023, b = rem >> 5, f4 = rem & 31;
    float4 v = *(const float4*)(x + ((size_t)b*NS + (t0+tp))*NI + f4*4);
    f16x4 h; h[0]=(f16)v.x; h[1]=(f16)v.y; h[2]=(f16)v.z; h[3]=(f16)v.w;
    *(f16x4*)&Xs[tp][b][f4*4] = h;
  }
  __syncthreads();
  for (int g = 0; g < 16; ++g) {
    f16x8 wIn[4];
    const float* wr = Win + (size_t)(g*64 + wv*16 + ln) * NI;
#pragma unroll
    for (int kt = 0; kt < 4; ++kt) wIn[kt] = cvt8(wr + kt*32 + q*8);
    for (int tp = 0; tp < 4; ++tp) {
      f32x4 m0 = {0,0,0,0}, m1 = {0,0,0,0};
#pragma unroll
      for (int kt = 0; kt < 4; ++kt) {
        f16x8 a0 = *(const f16x8*)&Xs[tp][ln][kt*32 + q*8];
        f16x8 a1 = *(const f16x8*)&Xs[tp][16 + ln][kt*32 + q*8];
        m0 = MFMA16(a0, wIn[kt], m0);
        m1 = MFMA16(a1, wIn[kt], m1);
      }
      f16x8 o8;
#pragma unroll
      for (int rg = 0; rg < 4; ++rg) { o8[rg] = (f16)m0[rg]; o8[4+rg] = (f16)m1[rg]; }
      *(f16x8*)&xpw[((((size_t)(t0+tp)*16 + g)*4 + wv)*64 + lane)*8] = o8;
    }
  }
}

// ---------------- kernel 2: the recurrence ----------------
// 256 WGs, 1/CU. 32 chunks x 8 WGs. Device-scope exchange.
// Per step: kt0..15 (half0) -> [odd: write half1 of h(s-1)] -> bar -> kt16..31
// -> publish -> vmcnt(0) -> SENTINEL (announce-early) -> SPECULATIVE sentinel
// pre-check issue -> xp-next loads -> readout -> vmcnt(0)+check; fallback poll
// only if peers lag -> issue gathers -> bar -> [even: write half0 | odd:
// y_combine] -> bar. Detect RT hidden under readout in the common case.
__global__ __launch_bounds__(256, 1) void esn_kernel(
    const f16* __restrict__ Wh, const f16* __restrict__ Woh,
    const float* __restrict__ Wob, float* __restrict__ out,
    const f16* __restrict__ xpw, unsigned* __restrict__ hbuf, int* __restrict__ sent)
{
  __shared__ __attribute__((aligned(16))) f16 Hs[NB][NR];       // 64 KB
  __shared__ __attribute__((aligned(16))) float Ys[4][NB][16];  // 8 KB readout partials

  const int tid  = threadIdx.x;
  const int lane = tid & 63;
  const int wv   = tid >> 6;   // 0..3
  const int q    = lane >> 4;
  const int ln   = lane & 15;
  const int sw   = ln & 7;     // LDS chunk swizzle key (rows ln and 16+ln share it)
  const int odd  = wv & 1;     // odd waves gather cols 512..1023

  const int bx = blockIdx.x;
  const int c  = (bx & 7)*4 + ((bx >> 3) & 3);
  const int g  = bx >> 5;      // 0..7

  const int warm = (c == 0) ? 0 : WARM;
  const int L    = CHUNK + warm;
  const int t0   = c*CHUNK - warm;

  // ---- W rows as MFMA B-fragments: nt covers cols g*128 + wv*32 + nt*16 + ln ----
  f16x8 wB[2][32];
#pragma unroll
  for (int nt = 0; nt < 2; ++nt) {
    const f16* wr = Wh + (size_t)(g*128 + wv*32 + nt*16 + ln) * NR;
#pragma unroll
    for (int kt = 0; kt < 32; ++kt) wB[nt][kt] = *(const f16x8*)(wr + kt*32 + q*8);
  }
  // ---- W_out fragments: out feature g*16 + ln; K-split kt in [wv*8, wv*8+8) ----
  f16x8 wO[8];
  {
    const f16* wr = Woh + (size_t)(g*16 + ln) * NR;
#pragma unroll
    for (int j = 0; j < 8; ++j) wO[j] = *(const f16x8*)(wr + (wv*8 + j)*32 + q*8);
  }
  float4 bz4 = *(const float4*)&Wob[g*16 + (lane & 3)*4];

  // h(-1) = 0
#pragma unroll
  for (int j = 0; j < 16; ++j) *(((f16x8*)&Hs[0][0]) + tid + j*256) = (f16x8){};

  const size_t xpu = ((size_t)(g*2 + (wv >> 1))*4 + (wv & 1)*2)*64 + lane;
  const f16x8* xpv = (const f16x8*)xpw;
  f16x8 xc0 = xpv[(size_t)t0*4096 + xpu];
  f16x8 xc1 = xpv[(size_t)t0*4096 + xpu + 64];
  __syncthreads();

  // own-half sentinel address for this lane (lanes 0-15 active in detect)
  const int hg = odd ? 4 : 0;
  const int* spl = &sent[((c*2)*NG + (hg + (lane >> 2)))*4 + (lane & 3)];

  auto y_combine = [&](int tg) {
    const int b  = ((wv >> 1) & 1)*16 + (lane >> 2);
    const int o4 = (lane & 3)*4;
    float4 s0 = *(const float4*)&Ys[0][b][o4];
    float4 s1 = *(const float4*)&Ys[1][b][o4];
    float4 s2 = *(const float4*)&Ys[2][b][o4];
    float4 s3 = *(const float4*)&Ys[3][b][o4];
    float4 r;
    r.x = s0.x + s1.x + s2.x + s3.x + bz4.x;
    r.y = s0.y + s1.y + s2.y + s3.y + bz4.y;
    r.z = s0.z + s1.z + s2.z + s3.z + bz4.z;
    r.w = s0.w + s1.w + s2.w + s3.w + bz4.w;
    *(float4*)&out[(size_t)b*(NS*NO) + (size_t)tg*NO + g*16 + o4] = r;
  };

  unsigned* Hw = (unsigned*)&Hs[0][0];
  u32x4 gbuf[16];

  for (int s = 0; s < L; ++s) {
    const int t  = t0 + s;
    const int pb = s & 1;

    // ---- A: kt 0..15 (needs only half0, ready at entry) ----
    f32x4 aE00 = {(float)xc0[0], (float)xc0[1], (float)xc0[2], (float)xc0[3]};
    f32x4 aE10 = {(float)xc0[4], (float)xc0[5], (float)xc0[6], (float)xc0[7]};
    f32x4 aE01 = {(float)xc1[0], (float)xc1[1], (float)xc1[2], (float)xc1[3]};
    f32x4 aE11 = {(float)xc1[4], (float)xc1[5], (float)xc1[6], (float)xc1[7]};
    f32x4 aO00 = {0,0,0,0}, aO10 = {0,0,0,0}, aO01 = {0,0,0,0}, aO11 = {0,0,0,0};
#pragma unroll
    for (int kt = 0; kt < 16; ++kt) {
      f16x8 h0 = *(const f16x8*)&Hs[ln]     [((kt*4 + q) ^ sw) * 8];
      f16x8 h1 = *(const f16x8*)&Hs[16 + ln][((kt*4 + q) ^ sw) * 8];
      if (kt & 1) {
        aO00 = MFMA16(h0, wB[0][kt], aO00); aO01 = MFMA16(h0, wB[1][kt], aO01);
        aO10 = MFMA16(h1, wB[0][kt], aO10); aO11 = MFMA16(h1, wB[1][kt], aO11);
      } else {
        aE00 = MFMA16(h0, wB[0][kt], aE00); aE01 = MFMA16(h0, wB[1][kt], aE01);
        aE10 = MFMA16(h1, wB[0][kt], aE10); aE11 = MFMA16(h1, wB[1][kt], aE11);
      }
    }

    // ---- odd waves: write half1 of h(s-1) (gathers a full step in flight) ----
    if (odd && s > 0) {
      asm volatile("s_waitcnt vmcnt(0)" ::: "memory");
      __builtin_amdgcn_sched_barrier(0);
#pragma unroll
      for (int j = 0; j < 16; ++j)
        *(u32x4*)(Hw + (size_t)(tid + j*256)*4) = gbuf[j];
    }
    __syncthreads();  // bar3: half1 of h(s-1) ready

    // ---- B: kt 16..31 ----
#pragma unroll
    for (int kt = 16; kt < 32; ++kt) {
      f16x8 h0 = *(const f16x8*)&Hs[ln]     [((kt*4 + q) ^ sw) * 8];
      f16x8 h1 = *(const f16x8*)&Hs[16 + ln][((kt*4 + q) ^ sw) * 8];
      if (kt & 1) {
        aO00 = MFMA16(h0, wB[0][kt], aO00); aO01 = MFMA16(h0, wB[1][kt], aO01);
        aO10 = MFMA16(h1, wB[0][kt], aO10); aO11 = MFMA16(h1, wB[1][kt], aO11);
      } else {
        aE00 = MFMA16(h0, wB[0][kt], aE00); aE01 = MFMA16(h0, wB[1][kt], aE01);
        aE10 = MFMA16(h1, wB[0][kt], aE10); aE11 = MFMA16(h1, wB[1][kt], aE11);
      }
    }
    f32x4 acc[2][2];
    acc[0][0] = aE00 + aO00; acc[0][1] = aE01 + aO01;
    acc[1][0] = aE10 + aO10; acc[1][1] = aE11 + aO11;

    // ---- C: tanh + pack + PRE-SWIZZLED device-scope publish ----
    unsigned* hbw = hbuf + (size_t)(c*2 + pb)*NB*512;
#pragma unroll
    for (int mh = 0; mh < 2; ++mh) {
#pragma unroll
      for (int nt = 0; nt < 2; ++nt) {
        const int dcol = g*64 + wv*16 + nt*8 + (ln >> 1);
        const int ck = dcol >> 2, e = dcol & 3;
#pragma unroll
        for (int rg = 0; rg < 4; ++rg) {
          float av = acc[mh][nt][rg];
          float e0 = __expf(2.f * av);
          float hv = 1.f - 2.f * __builtin_amdgcn_rcpf(e0 + 1.f);
          unsigned u = (unsigned)__builtin_bit_cast(unsigned short, (f16)hv);
          unsigned o = (unsigned)__shfl_xor((int)u, 1);
          unsigned pk = (ln & 1) ? (o | (u << 16)) : (u | (o << 16));
          if (((rg ^ ln) & 1) == 0) {
            int b = mh*16 + q*4 + rg;
            int sd = ((ck ^ (b & 7)) << 2) | e;
            __hip_atomic_store(&hbw[b*512 + sd], pk, __ATOMIC_RELAXED, __HIP_MEMORY_SCOPE_AGENT);
          }
        }
      }
    }

    // ---- D: drain publishes + announce-early ----
    asm volatile("s_waitcnt vmcnt(0)" ::: "memory");
    if (lane == 0)
      __hip_atomic_store(&sent[((c*2 + pb)*NG + g)*4 + wv], s + 1,
                         __ATOMIC_RELAXED, __HIP_MEMORY_SCOPE_AGENT);

    // ---- D2: speculative pre-check issue (flies under readout) ----
    int pre = 0x7fffffff;  // lanes >= 16 trivially pass
    if (lane < 16) {
      const int* sp = spl + pb*NG*4;
      asm volatile("global_load_dword %0, %1, off sc0 sc1"
                   : "=v"(pre) : "v"(sp) : "memory");
    }

    // ---- E: xp-next loads (off the drain path) ----
    f16x8 xn0 = (f16x8){}, xn1 = (f16x8){};
    if (s + 1 < L) {
      xn0 = xpv[(size_t)(t+1)*4096 + xpu];
      xn1 = xpv[(size_t)(t+1)*4096 + xpu + 64];
    }

    // ---- F: readout partials y(t-1) (reads full Hs = h(s-1)) ----
    const bool do_ro = (s > warm);
    if (do_ro) {
      f32x4 y0 = {0,0,0,0}, y1 = {0,0,0,0};
#pragma unroll
      for (int j = 0; j < 8; ++j) {
        int kt = wv*8 + j;
        f16x8 h0 = *(const f16x8*)&Hs[ln]     [((kt*4 + q) ^ sw) * 8];
        f16x8 h1 = *(const f16x8*)&Hs[16 + ln][((kt*4 + q) ^ sw) * 8];
        y0 = MFMA16(h0, wO[j], y0);
        y1 = MFMA16(h1, wO[j], y1);
      }
#pragma unroll
      for (int rg = 0; rg < 4; ++rg) {
        Ys[wv][q*4 + rg][ln]      = y0[rg];
        Ys[wv][16 + q*4 + rg][ln] = y1[rg];
      }
    }

    // ---- G: check pre-fetched sentinels; fallback poll only if peers lag ----
    asm volatile("s_waitcnt vmcnt(0)" ::: "memory");
    __builtin_amdgcn_sched_barrier(0);
    if (!__all(pre >= s + 1)) {
      if (lane < 16) {
        const int* sp = spl + pb*NG*4;
        long long dl = clock64() + 10000000LL;  // watchdog ~4 ms
        while (__hip_atomic_load(sp, __ATOMIC_RELAXED, __HIP_MEMORY_SCOPE_AGENT) < s + 1) {
          if (clock64() > dl) break;
        }
      }
    }

    // ---- H: issue gathers (each thread's 16 chunks are in its wave's half) ----
    {
      const u32x4* src = (const u32x4*)hbw;
#pragma unroll
      for (int j = 0; j < 16; ++j) {
        const u32x4* p = src + tid + j*256;
        asm volatile("global_load_dwordx4 %0, %1, off sc0 sc1"
                     : "=&v"(gbuf[j]) : "v"(p) : "memory");
      }
    }

    __syncthreads();  // bar1: all old-Hs reads (A,B,F) done before overwrite

    // ---- J: even waves write half0 of h(s); odd waves combine y(t-1) ----
    if (!odd) {
      asm volatile("s_waitcnt vmcnt(0)" ::: "memory");
      __builtin_amdgcn_sched_barrier(0);
#pragma unroll
      for (int j = 0; j < 16; ++j)
        *(u32x4*)(Hw + (size_t)(tid + j*256)*4) = gbuf[j];
    } else if (do_ro) {
      y_combine(t - 1);
    }

    xc0 = xn0; xc1 = xn1;
    __syncthreads();  // bar2: half0 of h(s) ready
  }

  // ---- epilogue: finish half1 of h(L-1), then final readout + combine ----
  if (odd) {
    asm volatile("s_waitcnt vmcnt(0)" ::: "memory");
    __builtin_amdgcn_sched_barrier(0);
#pragma unroll
    for (int j = 0; j < 16; ++j)
      *(u32x4*)(Hw + (size_t)(tid + j*256)*4) = gbuf[j];
  }
  __syncthreads();
  {
    f32x4 y0 = {0,0,0,0}, y1 = {0,0,0,0};
#pragma unroll
    for (int j = 0; j < 8; ++j) {
      int kt = wv*8 + j;
      f16x8 h0 = *(const f16x8*)&Hs[ln]     [((kt*4 + q) ^ sw) * 8];
      f16x8 h1 = *(const f16x8*)&Hs[16 + ln][((kt*4 + q) ^ sw) * 8];
      y0 = MFMA16(h0, wO[j], y0);
      y1 = MFMA16(h1, wO[j], y1);
    }
#pragma unroll
    for (int rg = 0; rg < 4; ++rg) {
      Ys[wv][q*4 + rg][ln]      = y0[rg];
      Ys[wv][16 + q*4 + rg][ln] = y1[rg];
    }
    __syncthreads();
    if (odd) y_combine(t0 + L - 1);
  }
}

extern "C" void kernel_launch(void* const* d_in, const int* in_sizes, int n_in,
                              void* d_out, int out_size, void* d_ws, size_t ws_size,
                              hipStream_t stream) {
  (void)in_sizes; (void)n_in; (void)out_size; (void)ws_size;
  const float* x   = (const float*)d_in[0];
  const float* Win = (const float*)d_in[1];
  const float* W   = (const float*)d_in[2];
  const float* Wow = (const float*)d_in[3];
  const float* Wob = (const float*)d_in[4];
  float* out = (float*)d_out;

  // workspace layout (~70.3 MB total)
  f16*      xpw  = (f16*)d_ws;                                   // 64 MiB
  unsigned* hbuf = (unsigned*)((char*)d_ws + 67108864);          // 4 MiB
  f16*      Wh   = (f16*)((char*)d_ws + 71303168);               // 2 MiB
  f16*      Woh  = (f16*)((char*)d_ws + 73400320);               // 256 KiB
  int*      sent = (int*)((char*)d_ws + 73662464);               // 8 KiB

  hipMemsetAsync(sent, 0, NC*2*NG*4*sizeof(int), stream);

  xp_kernel<<<dim3(NS/4), dim3(256), 0, stream>>>(x, Win, xpw, W, Wow, Wh, Woh);
  esn_kernel<<<dim3(NC*NG), dim3(256), 0, stream>>>(Wh, Woh, Wob, out, xpw, hbuf, sent);
}

// Round 10
// 384.225 us; speedup vs baseline: 1.1479x; 1.1479x over previous
//
#include <hip/hip_runtime.h>

typedef _Float16 f16;
typedef _Float16 f16x8 __attribute__((ext_vector_type(8)));
typedef _Float16 f16x4 __attribute__((ext_vector_type(4)));
typedef float f32x4 __attribute__((ext_vector_type(4)));
typedef unsigned u32x4 __attribute__((ext_vector_type(4)));

#define NB 32
#define NS 1024
#define NI 128
#define NR 1024
#define NO 128
#define NG 8       // workgroups per chunk (each WG owns 128 columns)
#define NC 32      // chunks
#define WARM 16    // warm-start depth (validated r7/r8)
#define CHUNK 32   // real steps per chunk -> 48 serial steps

#define MFMA16(a,b,c) __builtin_amdgcn_mfma_f32_16x16x32_f16((a),(b),(c),0,0,0)

__device__ inline f16x8 cvt8(const float* p) {
  float4 a = *(const float4*)p, b = *(const float4*)(p + 4);
  f16x8 v;
  v[0]=(f16)a.x; v[1]=(f16)a.y; v[2]=(f16)a.z; v[3]=(f16)a.w;
  v[4]=(f16)b.x; v[5]=(f16)b.y; v[6]=(f16)b.z; v[7]=(f16)b.w;
  return v;
}

// ---------------- kernel 1: W/W_out f16 preconvert + x_proj[t] in MFMA C-frag order ----
__global__ __launch_bounds__(256) void xp_kernel(
    const float* __restrict__ x, const float* __restrict__ Win, f16* __restrict__ xpw,
    const float* __restrict__ W, const float* __restrict__ Wow,
    f16* __restrict__ Wh, f16* __restrict__ Woh)
{
  __shared__ __attribute__((aligned(16))) f16 Xs[4][32][136];  // 34.8 KB
  const int tid = threadIdx.x, lane = tid & 63, wv = tid >> 6;
  const int q = lane >> 4, ln = lane & 15;
  const int t0 = blockIdx.x * 4;

  // ---- merged conv: 65536 threads convert W (1M f32, 4xfloat4 each) + Wow (128K, 2x) ----
  {
    const int base = blockIdx.x * 256 + tid;
#pragma unroll
    for (int k = 0; k < 4; ++k) {
      int i = base + k * 65536;
      float4 v = *(const float4*)(W + (size_t)i * 4);
      f16x4 h; h[0]=(f16)v.x; h[1]=(f16)v.y; h[2]=(f16)v.z; h[3]=(f16)v.w;
      *(f16x4*)&Wh[(size_t)i * 4] = h;
    }
#pragma unroll
    for (int k = 0; k < 2; ++k) {
      int i = base + k * 65536;
      if (i < NO * NR / 4) {
        float4 v = *(const float4*)(Wow + (size_t)i * 4);
        f16x4 h; h[0]=(f16)v.x; h[1]=(f16)v.y; h[2]=(f16)v.z; h[3]=(f16)v.w;
        *(f16x4*)&Woh[(size_t)i * 4] = h;
      }
    }
  }

#pragma unroll
  for (int j = 0; j < 16; ++j) {
    int idx = tid + j*256;
    int tp = idx >> 10, rem = idx & 1023, b = rem >> 5, f4 = rem & 31;
    float4 v = *(const float4*)(x + ((size_t)b*NS + (t0+tp))*NI + f4*4);
    f16x4 h; h[0]=(f16)v.x; h[1]=(f16)v.y; h[2]=(f16)v.z; h[3]=(f16)v.w;
    *(f16x4*)&Xs[tp][b][f4*4] = h;
  }
  __syncthreads();
  for (int g = 0; g < 16; ++g) {
    f16x8 wIn[4];
    const float* wr = Win + (size_t)(g*64 + wv*16 + ln) * NI;
#pragma unroll
    for (int kt = 0; kt < 4; ++kt) wIn[kt] = cvt8(wr + kt*32 + q*8);
    for (int tp = 0; tp < 4; ++tp) {
      f32x4 m0 = {0,0,0,0}, m1 = {0,0,0,0};
#pragma unroll
      for (int kt = 0; kt < 4; ++kt) {
        f16x8 a0 = *(const f16x8*)&Xs[tp][ln][kt*32 + q*8];
        f16x8 a1 = *(const f16x8*)&Xs[tp][16 + ln][kt*32 + q*8];
        m0 = MFMA16(a0, wIn[kt], m0);
        m1 = MFMA16(a1, wIn[kt], m1);
      }
      f16x8 o8;
#pragma unroll
      for (int rg = 0; rg < 4; ++rg) { o8[rg] = (f16)m0[rg]; o8[4+rg] = (f16)m1[rg]; }
      *(f16x8*)&xpw[((((size_t)(t0+tp)*16 + g)*4 + wv)*64 + lane)*8] = o8;
    }
  }
}

// ---------------- kernel 2: the recurrence ----------------
// 256 WGs, 1/CU. 32 chunks x 8 WGs. Device-scope exchange (r8 structure, proven).
// Per step: kt0..15 (half0) -> [odd: staged write half1 of h(s-1)] -> bar ->
// kt16..31 -> publish -> vmcnt(0) -> SENTINEL (announce-early) -> xp-next ->
// readout -> poll own-half sentinels (post-readout; r9 proved speculation fails)
// -> issue gathers -> bar -> [even: staged write half0 | odd: y_combine] -> bar.
__global__ __launch_bounds__(256, 1) void esn_kernel(
    const f16* __restrict__ Wh, const f16* __restrict__ Woh,
    const float* __restrict__ Wob, float* __restrict__ out,
    const f16* __restrict__ xpw, unsigned* __restrict__ hbuf, int* __restrict__ sent)
{
  __shared__ __attribute__((aligned(16))) f16 Hs[NB][NR];       // 64 KB
  __shared__ __attribute__((aligned(16))) float Ys[4][NB][16];  // 8 KB readout partials

  const int tid  = threadIdx.x;
  const int lane = tid & 63;
  const int wv   = tid >> 6;   // 0..3
  const int q    = lane >> 4;
  const int ln   = lane & 15;
  const int sw   = ln & 7;     // LDS chunk swizzle key (rows ln and 16+ln share it)
  const int odd  = wv & 1;     // odd waves gather cols 512..1023

  const int bx = blockIdx.x;
  const int c  = (bx & 7)*4 + ((bx >> 3) & 3);
  const int g  = bx >> 5;      // 0..7

  const int warm = (c == 0) ? 0 : WARM;
  const int L    = CHUNK + warm;
  const int t0   = c*CHUNK - warm;

  // ---- W rows as MFMA B-fragments: nt covers cols g*128 + wv*32 + nt*16 + ln ----
  f16x8 wB[2][32];
#pragma unroll
  for (int nt = 0; nt < 2; ++nt) {
    const f16* wr = Wh + (size_t)(g*128 + wv*32 + nt*16 + ln) * NR;
#pragma unroll
    for (int kt = 0; kt < 32; ++kt) wB[nt][kt] = *(const f16x8*)(wr + kt*32 + q*8);
  }
  // ---- W_out fragments: out feature g*16 + ln; K-split kt in [wv*8, wv*8+8) ----
  f16x8 wO[8];
  {
    const f16* wr = Woh + (size_t)(g*16 + ln) * NR;
#pragma unroll
    for (int j = 0; j < 8; ++j) wO[j] = *(const f16x8*)(wr + (wv*8 + j)*32 + q*8);
  }
  float4 bz4 = *(const float4*)&Wob[g*16 + (lane & 3)*4];

  // h(-1) = 0
#pragma unroll
  for (int j = 0; j < 16; ++j) *(((f16x8*)&Hs[0][0]) + tid + j*256) = (f16x8){};

  const size_t xpu = ((size_t)(g*2 + (wv >> 1))*4 + (wv & 1)*2)*64 + lane;
  const f16x8* xpv = (const f16x8*)xpw;
  f16x8 xc0 = xpv[(size_t)t0*4096 + xpu];
  f16x8 xc1 = xpv[(size_t)t0*4096 + xpu + 64];
  __syncthreads();

  // own-half sentinel base for this lane (lanes 0-15 active in detect)
  const int hg = odd ? 4 : 0;
  const int* spl = &sent[((c*2)*NG + (hg + (lane >> 2)))*4 + (lane & 3)];

  auto y_combine = [&](int tg) {
    const int b  = ((wv >> 1) & 1)*16 + (lane >> 2);
    const int o4 = (lane & 3)*4;
    float4 s0 = *(const float4*)&Ys[0][b][o4];
    float4 s1 = *(const float4*)&Ys[1][b][o4];
    float4 s2 = *(const float4*)&Ys[2][b][o4];
    float4 s3 = *(const float4*)&Ys[3][b][o4];
    float4 r;
    r.x = s0.x + s1.x + s2.x + s3.x + bz4.x;
    r.y = s0.y + s1.y + s2.y + s3.y + bz4.y;
    r.z = s0.z + s1.z + s2.z + s3.z + bz4.z;
    r.w = s0.w + s1.w + s2.w + s3.w + bz4.w;
    *(float4*)&out[(size_t)b*(NS*NO) + (size_t)tg*NO + g*16 + o4] = r;
  };

  unsigned* Hw = (unsigned*)&Hs[0][0];
  u32x4 gbuf[16];

  for (int s = 0; s < L; ++s) {
    const int t  = t0 + s;
    const int pb = s & 1;

    // ---- A: kt 0..15 (needs only half0, ready at entry) ----
    f32x4 aE00 = {(float)xc0[0], (float)xc0[1], (float)xc0[2], (float)xc0[3]};
    f32x4 aE10 = {(float)xc0[4], (float)xc0[5], (float)xc0[6], (float)xc0[7]};
    f32x4 aE01 = {(float)xc1[0], (float)xc1[1], (float)xc1[2], (float)xc1[3]};
    f32x4 aE11 = {(float)xc1[4], (float)xc1[5], (float)xc1[6], (float)xc1[7]};
    f32x4 aO00 = {0,0,0,0}, aO10 = {0,0,0,0}, aO01 = {0,0,0,0}, aO11 = {0,0,0,0};
#pragma unroll
    for (int kt = 0; kt < 16; ++kt) {
      f16x8 h0 = *(const f16x8*)&Hs[ln]     [((kt*4 + q) ^ sw) * 8];
      f16x8 h1 = *(const f16x8*)&Hs[16 + ln][((kt*4 + q) ^ sw) * 8];
      if (kt & 1) {
        aO00 = MFMA16(h0, wB[0][kt], aO00); aO01 = MFMA16(h0, wB[1][kt], aO01);
        aO10 = MFMA16(h1, wB[0][kt], aO10); aO11 = MFMA16(h1, wB[1][kt], aO11);
      } else {
        aE00 = MFMA16(h0, wB[0][kt], aE00); aE01 = MFMA16(h0, wB[1][kt], aE01);
        aE10 = MFMA16(h1, wB[0][kt], aE10); aE11 = MFMA16(h1, wB[1][kt], aE11);
      }
    }

    // ---- odd waves: staged write of half1 of h(s-1) (loads a full step in
    //      flight; vmcnt(8) covers gbuf[0..7] -- oldest-first semantics) ----
    if (odd && s > 0) {
      asm volatile("s_waitcnt vmcnt(8)" ::: "memory");
      __builtin_amdgcn_sched_barrier(0);
#pragma unroll
      for (int j = 0; j < 8; ++j)
        *(u32x4*)(Hw + (size_t)(tid + j*256)*4) = gbuf[j];
      asm volatile("s_waitcnt vmcnt(0)" ::: "memory");
      __builtin_amdgcn_sched_barrier(0);
#pragma unroll
      for (int j = 8; j < 16; ++j)
        *(u32x4*)(Hw + (size_t)(tid + j*256)*4) = gbuf[j];
    }
    __syncthreads();  // bar3: half1 of h(s-1) ready

    // ---- B: kt 16..31 ----
#pragma unroll
    for (int kt = 16; kt < 32; ++kt) {
      f16x8 h0 = *(const f16x8*)&Hs[ln]     [((kt*4 + q) ^ sw) * 8];
      f16x8 h1 = *(const f16x8*)&Hs[16 + ln][((kt*4 + q) ^ sw) * 8];
      if (kt & 1) {
        aO00 = MFMA16(h0, wB[0][kt], aO00); aO01 = MFMA16(h0, wB[1][kt], aO01);
        aO10 = MFMA16(h1, wB[0][kt], aO10); aO11 = MFMA16(h1, wB[1][kt], aO11);
      } else {
        aE00 = MFMA16(h0, wB[0][kt], aE00); aE01 = MFMA16(h0, wB[1][kt], aE01);
        aE10 = MFMA16(h1, wB[0][kt], aE10); aE11 = MFMA16(h1, wB[1][kt], aE11);
      }
    }
    f32x4 acc[2][2];
    acc[0][0] = aE00 + aO00; acc[0][1] = aE01 + aO01;
    acc[1][0] = aE10 + aO10; acc[1][1] = aE11 + aO11;

    // ---- C: tanh + pack + PRE-SWIZZLED device-scope publish ----
    unsigned* hbw = hbuf + (size_t)(c*2 + pb)*NB*512;
#pragma unroll
    for (int mh = 0; mh < 2; ++mh) {
#pragma unroll
      for (int nt = 0; nt < 2; ++nt) {
        const int dcol = g*64 + wv*16 + nt*8 + (ln >> 1);
        const int ck = dcol >> 2, e = dcol & 3;
#pragma unroll
        for (int rg = 0; rg < 4; ++rg) {
          float av = acc[mh][nt][rg];
          float e0 = __expf(2.f * av);
          float hv = 1.f - 2.f * __builtin_amdgcn_rcpf(e0 + 1.f);
          unsigned u = (unsigned)__builtin_bit_cast(unsigned short, (f16)hv);
          unsigned o = (unsigned)__shfl_xor((int)u, 1);
          unsigned pk = (ln & 1) ? (o | (u << 16)) : (u | (o << 16));
          if (((rg ^ ln) & 1) == 0) {
            int b = mh*16 + q*4 + rg;
            int sd = ((ck ^ (b & 7)) << 2) | e;
            __hip_atomic_store(&hbw[b*512 + sd], pk, __ATOMIC_RELAXED, __HIP_MEMORY_SCOPE_AGENT);
          }
        }
      }
    }

    // ---- D: drain publishes + announce-early ----
    asm volatile("s_waitcnt vmcnt(0)" ::: "memory");
    if (lane == 0)
      __hip_atomic_store(&sent[((c*2 + pb)*NG + g)*4 + wv], s + 1,
                         __ATOMIC_RELAXED, __HIP_MEMORY_SCOPE_AGENT);

    // ---- E: xp-next loads (off the drain path) ----
    f16x8 xn0 = (f16x8){}, xn1 = (f16x8){};
    if (s + 1 < L) {
      xn0 = xpv[(size_t)(t+1)*4096 + xpu];
      xn1 = xpv[(size_t)(t+1)*4096 + xpu + 64];
    }

    // ---- F: readout partials y(t-1) (reads full Hs = h(s-1)) ----
    const bool do_ro = (s > warm);
    if (do_ro) {
      f32x4 y0 = {0,0,0,0}, y1 = {0,0,0,0};
#pragma unroll
      for (int j = 0; j < 8; ++j) {
        int kt = wv*8 + j;
        f16x8 h0 = *(const f16x8*)&Hs[ln]     [((kt*4 + q) ^ sw) * 8];
        f16x8 h1 = *(const f16x8*)&Hs[16 + ln][((kt*4 + q) ^ sw) * 8];
        y0 = MFMA16(h0, wO[j], y0);
        y1 = MFMA16(h1, wO[j], y1);
      }
#pragma unroll
      for (int rg = 0; rg < 4; ++rg) {
        Ys[wv][q*4 + rg][ln]      = y0[rg];
        Ys[wv][16 + q*4 + rg][ln] = y1[rg];
      }
    }

    // ---- G: poll own-half sentinels (post-readout; cheap spin, rare clock) ----
    if (lane < 16) {
      const int* sp = spl + pb*NG*4;
      long long dl = clock64() + 10000000LL;  // watchdog ~4 ms
      int spin = 0;
      while (__hip_atomic_load(sp, __ATOMIC_RELAXED, __HIP_MEMORY_SCOPE_AGENT) < s + 1) {
        if (((++spin) & 15) == 0 && clock64() > dl) break;
      }
    }

    // ---- H: issue gathers (each thread's 16 chunks are in its wave's half) ----
    {
      const u32x4* src = (const u32x4*)hbw;
#pragma unroll
      for (int j = 0; j < 16; ++j) {
        const u32x4* p = src + tid + j*256;
        asm volatile("global_load_dwordx4 %0, %1, off sc0 sc1"
                     : "=&v"(gbuf[j]) : "v"(p) : "memory");
      }
    }

    __syncthreads();  // bar1: all old-Hs reads (A,B,F) done before overwrite

    // ---- J: even waves staged-write half0 of h(s); odd waves combine y(t-1) ----
    if (!odd) {
      asm volatile("s_waitcnt vmcnt(8)" ::: "memory");
      __builtin_amdgcn_sched_barrier(0);
#pragma unroll
      for (int j = 0; j < 8; ++j)
        *(u32x4*)(Hw + (size_t)(tid + j*256)*4) = gbuf[j];
      asm volatile("s_waitcnt vmcnt(0)" ::: "memory");
      __builtin_amdgcn_sched_barrier(0);
#pragma unroll
      for (int j = 8; j < 16; ++j)
        *(u32x4*)(Hw + (size_t)(tid + j*256)*4) = gbuf[j];
    } else if (do_ro) {
      y_combine(t - 1);
    }

    xc0 = xn0; xc1 = xn1;
    __syncthreads();  // bar2: half0 of h(s) ready
  }

  // ---- epilogue: finish half1 of h(L-1), then final readout + combine ----
  if (odd) {
    asm volatile("s_waitcnt vmcnt(0)" ::: "memory");
    __builtin_amdgcn_sched_barrier(0);
#pragma unroll
    for (int j = 0; j < 16; ++j)
      *(u32x4*)(Hw + (size_t)(tid + j*256)*4) = gbuf[j];
  }
  __syncthreads();
  {
    f32x4 y0 = {0,0,0,0}, y1 = {0,0,0,0};
#pragma unroll
    for (int j = 0; j < 8; ++j) {
      int kt = wv*8 + j;
      f16x8 h0 = *(const f16x8*)&Hs[ln]     [((kt*4 + q) ^ sw) * 8];
      f16x8 h1 = *(const f16x8*)&Hs[16 + ln][((kt*4 + q) ^ sw) * 8];
      y0 = MFMA16(h0, wO[j], y0);
      y1 = MFMA16(h1, wO[j], y1);
    }
#pragma unroll
    for (int rg = 0; rg < 4; ++rg) {
      Ys[wv][q*4 + rg][ln]      = y0[rg];
      Ys[wv][16 + q*4 + rg][ln] = y1[rg];
    }
    __syncthreads();
    if (odd) y_combine(t0 + L - 1);
  }
}

extern "C" void kernel_launch(void* const* d_in, const int* in_sizes, int n_in,
                              void* d_out, int out_size, void* d_ws, size_t ws_size,
                              hipStream_t stream) {
  (void)in_sizes; (void)n_in; (void)out_size; (void)ws_size;
  const float* x   = (const float*)d_in[0];
  const float* Win = (const float*)d_in[1];
  const float* W   = (const float*)d_in[2];
  const float* Wow = (const float*)d_in[3];
  const float* Wob = (const float*)d_in[4];
  float* out = (float*)d_out;

  // workspace layout (~70.3 MB total)
  f16*      xpw  = (f16*)d_ws;                                   // 64 MiB
  unsigned* hbuf = (unsigned*)((char*)d_ws + 67108864);          // 4 MiB
  f16*      Wh   = (f16*)((char*)d_ws + 71303168);               // 2 MiB
  f16*      Woh  = (f16*)((char*)d_ws + 73400320);               // 256 KiB
  int*      sent = (int*)((char*)d_ws + 73662464);               // 8 KiB

  hipMemsetAsync(sent, 0, NC*2*NG*4*sizeof(int), stream);

  xp_kernel<<<dim3(NS/4), dim3(256), 0, stream>>>(x, Win, xpw, W, Wow, Wh, Woh);
  esn_kernel<<<dim3(NC*NG), dim3(256), 0, stream>>>(Wh, Woh, Wob, out, xpw, hbuf, sent);
}

// Round 11
// 373.617 us; speedup vs baseline: 1.1805x; 1.0284x over previous
//
#include <hip/hip_runtime.h>

typedef _Float16 f16;
typedef _Float16 f16x8 __attribute__((ext_vector_type(8)));
typedef _Float16 f16x4 __attribute__((ext_vector_type(4)));
typedef float f32x4 __attribute__((ext_vector_type(4)));
typedef unsigned u32x4 __attribute__((ext_vector_type(4)));

#define NB 32
#define NS 1024
#define NI 128
#define NR 1024
#define NO 128
#define NG 8       // workgroups per chunk (each WG owns 128 columns)
#define NC 32      // chunks
#define WARM 12    // warm-start depth: 0.6^12 ~ 2e-3 trunc, 3x under f16 noise floor
#define CHUNK 32   // real steps per chunk -> 44 serial steps

#define MFMA16(a,b,c) __builtin_amdgcn_mfma_f32_16x16x32_f16((a),(b),(c),0,0,0)

__device__ inline f16x8 cvt8(const float* p) {
  float4 a = *(const float4*)p, b = *(const float4*)(p + 4);
  f16x8 v;
  v[0]=(f16)a.x; v[1]=(f16)a.y; v[2]=(f16)a.z; v[3]=(f16)a.w;
  v[4]=(f16)b.x; v[5]=(f16)b.y; v[6]=(f16)b.z; v[7]=(f16)b.w;
  return v;
}

// ---------------- kernel 1: W/W_out f16 preconvert + x_proj[t] in MFMA C-frag order ----
__global__ __launch_bounds__(256) void xp_kernel(
    const float* __restrict__ x, const float* __restrict__ Win, f16* __restrict__ xpw,
    const float* __restrict__ W, const float* __restrict__ Wow,
    f16* __restrict__ Wh, f16* __restrict__ Woh)
{
  __shared__ __attribute__((aligned(16))) f16 Xs[4][32][136];  // 34.8 KB
  const int tid = threadIdx.x, lane = tid & 63, wv = tid >> 6;
  const int q = lane >> 4, ln = lane & 15;
  const int t0 = blockIdx.x * 4;

  // ---- merged conv: 65536 threads convert W (1M f32, 4xfloat4 each) + Wow (128K, 2x) ----
  {
    const int base = blockIdx.x * 256 + tid;
#pragma unroll
    for (int k = 0; k < 4; ++k) {
      int i = base + k * 65536;
      float4 v = *(const float4*)(W + (size_t)i * 4);
      f16x4 h; h[0]=(f16)v.x; h[1]=(f16)v.y; h[2]=(f16)v.z; h[3]=(f16)v.w;
      *(f16x4*)&Wh[(size_t)i * 4] = h;
    }
#pragma unroll
    for (int k = 0; k < 2; ++k) {
      int i = base + k * 65536;
      if (i < NO * NR / 4) {
        float4 v = *(const float4*)(Wow + (size_t)i * 4);
        f16x4 h; h[0]=(f16)v.x; h[1]=(f16)v.y; h[2]=(f16)v.z; h[3]=(f16)v.w;
        *(f16x4*)&Woh[(size_t)i * 4] = h;
      }
    }
  }

#pragma unroll
  for (int j = 0; j < 16; ++j) {
    int idx = tid + j*256;
    int tp = idx >> 10, rem = idx & 1023, b = rem >> 5, f4 = rem & 31;
    float4 v = *(const float4*)(x + ((size_t)b*NS + (t0+tp))*NI + f4*4);
    f16x4 h; h[0]=(f16)v.x; h[1]=(f16)v.y; h[2]=(f16)v.z; h[3]=(f16)v.w;
    *(f16x4*)&Xs[tp][b][f4*4] = h;
  }
  __syncthreads();
  for (int g = 0; g < 16; ++g) {
    f16x8 wIn[4];
    const float* wr = Win + (size_t)(g*64 + wv*16 + ln) * NI;
#pragma unroll
    for (int kt = 0; kt < 4; ++kt) wIn[kt] = cvt8(wr + kt*32 + q*8);
    for (int tp = 0; tp < 4; ++tp) {
      f32x4 m0 = {0,0,0,0}, m1 = {0,0,0,0};
#pragma unroll
      for (int kt = 0; kt < 4; ++kt) {
        f16x8 a0 = *(const f16x8*)&Xs[tp][ln][kt*32 + q*8];
        f16x8 a1 = *(const f16x8*)&Xs[tp][16 + ln][kt*32 + q*8];
        m0 = MFMA16(a0, wIn[kt], m0);
        m1 = MFMA16(a1, wIn[kt], m1);
      }
      f16x8 o8;
#pragma unroll
      for (int rg = 0; rg < 4; ++rg) { o8[rg] = (f16)m0[rg]; o8[4+rg] = (f16)m1[rg]; }
      *(f16x8*)&xpw[((((size_t)(t0+tp)*16 + g)*4 + wv)*64 + lane)*8] = o8;
    }
  }
}

// ---------------- kernel 2: the recurrence ----------------
// 256 WGs, 1/CU. 32 chunks x 8 WGs. Device-scope exchange (r10 primitives).
// Half0 of h is DOUBLE-BUFFERED (Hs0[2]); Ys double-buffered; y_combine deferred
// one step -> bar1 eliminated (2 barriers/step). Per step:
// A(kt0-15, Hs0[rb]) -> [odd: staged write half1 h(s-1) -> Hs1] -> bar3 ->
// B(kt16-31, Hs1) -> publish -> vmcnt(0) -> announce -> xp -> F(readout->Ys[cur])
// -> poll -> issue gathers -> [even: staged write half0 h(s)->Hs0[cur] |
// odd: combine y(t-2) from Ys[rb]] -> bar2.
__global__ __launch_bounds__(256, 1) void esn_kernel(
    const f16* __restrict__ Wh, const f16* __restrict__ Woh,
    const float* __restrict__ Wob, float* __restrict__ out,
    const f16* __restrict__ xpw, unsigned* __restrict__ hbuf, int* __restrict__ sent)
{
  __shared__ __attribute__((aligned(16))) f16 Hs0[2][NB][512];   // 64 KB half0 dbuf
  __shared__ __attribute__((aligned(16))) f16 Hs1[NB][512];      // 32 KB half1
  __shared__ __attribute__((aligned(16))) float Ys[2][4][NB][16];// 16 KB readout dbuf

  const int tid  = threadIdx.x;
  const int lane = tid & 63;
  const int wv   = tid >> 6;   // 0..3
  const int q    = lane >> 4;
  const int ln   = lane & 15;
  const int sw   = ln & 7;     // LDS chunk swizzle key
  const int odd  = wv & 1;     // odd waves gather/write half1 (cols 512..1023)
  const int wr0  = tid >> 7;   // gather row parity
  const int wcl  = tid & 63;   // gather chunk-in-half

  const int bx = blockIdx.x;
  const int c  = (bx & 7)*4 + ((bx >> 3) & 3);
  const int g  = bx >> 5;      // 0..7

  const int warm = (c == 0) ? 0 : WARM;
  const int L    = CHUNK + warm;
  const int t0   = c*CHUNK - warm;

  // ---- W rows as MFMA B-fragments ----
  f16x8 wB[2][32];
#pragma unroll
  for (int nt = 0; nt < 2; ++nt) {
    const f16* wr = Wh + (size_t)(g*128 + wv*32 + nt*16 + ln) * NR;
#pragma unroll
    for (int kt = 0; kt < 32; ++kt) wB[nt][kt] = *(const f16x8*)(wr + kt*32 + q*8);
  }
  // ---- W_out fragments: K-split kt in [wv*8, wv*8+8) ----
  f16x8 wO[8];
  {
    const f16* wr = Woh + (size_t)(g*16 + ln) * NR;
#pragma unroll
    for (int j = 0; j < 8; ++j) wO[j] = *(const f16x8*)(wr + (wv*8 + j)*32 + q*8);
  }
  float4 bz4 = *(const float4*)&Wob[g*16 + (lane & 3)*4];

  // h(-1) = 0 in all buffers
#pragma unroll
  for (int j = 0; j < 8; ++j) {
    *(((f16x8*)&Hs0[0][0][0]) + tid + j*256) = (f16x8){};
    *(((f16x8*)&Hs0[1][0][0]) + tid + j*256) = (f16x8){};
    *(((f16x8*)&Hs1[0][0])    + tid + j*256) = (f16x8){};
  }

  const size_t xpu = ((size_t)(g*2 + (wv >> 1))*4 + (wv & 1)*2)*64 + lane;
  const f16x8* xpv = (const f16x8*)xpw;
  f16x8 xc0 = xpv[(size_t)t0*4096 + xpu];
  f16x8 xc1 = xpv[(size_t)t0*4096 + xpu + 64];
  __syncthreads();

  // own-half sentinel base (lanes 0-15 active in detect)
  const int hg = odd ? 4 : 0;
  const int* spl = &sent[((c*2)*NG + (hg + (lane >> 2)))*4 + (lane & 3)];

  auto y_combine = [&](int yb, int tg) {
    const int b  = ((wv >> 1) & 1)*16 + (lane >> 2);
    const int o4 = (lane & 3)*4;
    float4 s0 = *(const float4*)&Ys[yb][0][b][o4];
    float4 s1 = *(const float4*)&Ys[yb][1][b][o4];
    float4 s2 = *(const float4*)&Ys[yb][2][b][o4];
    float4 s3 = *(const float4*)&Ys[yb][3][b][o4];
    float4 r;
    r.x = s0.x + s1.x + s2.x + s3.x + bz4.x;
    r.y = s0.y + s1.y + s2.y + s3.y + bz4.y;
    r.z = s0.z + s1.z + s2.z + s3.z + bz4.z;
    r.w = s0.w + s1.w + s2.w + s3.w + bz4.w;
    *(float4*)&out[(size_t)b*(NS*NO) + (size_t)tg*NO + g*16 + o4] = r;
  };

  u32x4 gbuf[16];
  u32x4* const dst1 = (u32x4*)&Hs1[0][0];

  for (int s = 0; s < L; ++s) {
    const int t   = t0 + s;
    const int pb  = s & 1;
    const int cur = s & 1, rb = cur ^ 1;

    // ---- A: kt 0..15, reads h(s-1) half0 from Hs0[rb] ----
    f32x4 aE00 = {(float)xc0[0], (float)xc0[1], (float)xc0[2], (float)xc0[3]};
    f32x4 aE10 = {(float)xc0[4], (float)xc0[5], (float)xc0[6], (float)xc0[7]};
    f32x4 aE01 = {(float)xc1[0], (float)xc1[1], (float)xc1[2], (float)xc1[3]};
    f32x4 aE11 = {(float)xc1[4], (float)xc1[5], (float)xc1[6], (float)xc1[7]};
    f32x4 aO00 = {0,0,0,0}, aO10 = {0,0,0,0}, aO01 = {0,0,0,0}, aO11 = {0,0,0,0};
#pragma unroll
    for (int kt = 0; kt < 16; ++kt) {
      f16x8 h0 = *(const f16x8*)&Hs0[rb][ln]     [((kt*4 + q) ^ sw) * 8];
      f16x8 h1 = *(const f16x8*)&Hs0[rb][16 + ln][((kt*4 + q) ^ sw) * 8];
      if (kt & 1) {
        aO00 = MFMA16(h0, wB[0][kt], aO00); aO01 = MFMA16(h0, wB[1][kt], aO01);
        aO10 = MFMA16(h1, wB[0][kt], aO10); aO11 = MFMA16(h1, wB[1][kt], aO11);
      } else {
        aE00 = MFMA16(h0, wB[0][kt], aE00); aE01 = MFMA16(h0, wB[1][kt], aE01);
        aE10 = MFMA16(h1, wB[0][kt], aE10); aE11 = MFMA16(h1, wB[1][kt], aE11);
      }
    }

    // ---- odd: staged write half1 of h(s-1) -> Hs1 (loads a full phase in flight) ----
    if (odd && s > 0) {
      asm volatile("s_waitcnt vmcnt(8)" ::: "memory");
      __builtin_amdgcn_sched_barrier(0);
#pragma unroll
      for (int j = 0; j < 8; ++j) dst1[(2*j + wr0)*64 + wcl] = gbuf[j];
      asm volatile("s_waitcnt vmcnt(0)" ::: "memory");
      __builtin_amdgcn_sched_barrier(0);
#pragma unroll
      for (int j = 8; j < 16; ++j) dst1[(2*j + wr0)*64 + wcl] = gbuf[j];
    }
    __syncthreads();  // bar3: half1 of h(s-1) ready

    // ---- B: kt 16..31, reads h(s-1) half1 from Hs1 ----
#pragma unroll
    for (int kt = 16; kt < 32; ++kt) {
      const int cB = (((kt - 16)*4 + q) ^ sw) * 8;
      f16x8 h0 = *(const f16x8*)&Hs1[ln][cB];
      f16x8 h1 = *(const f16x8*)&Hs1[16 + ln][cB];
      if (kt & 1) {
        aO00 = MFMA16(h0, wB[0][kt], aO00); aO01 = MFMA16(h0, wB[1][kt], aO01);
        aO10 = MFMA16(h1, wB[0][kt], aO10); aO11 = MFMA16(h1, wB[1][kt], aO11);
      } else {
        aE00 = MFMA16(h0, wB[0][kt], aE00); aE01 = MFMA16(h0, wB[1][kt], aE01);
        aE10 = MFMA16(h1, wB[0][kt], aE10); aE11 = MFMA16(h1, wB[1][kt], aE11);
      }
    }
    f32x4 acc[2][2];
    acc[0][0] = aE00 + aO00; acc[0][1] = aE01 + aO01;
    acc[1][0] = aE10 + aO10; acc[1][1] = aE11 + aO11;

    // ---- C: tanh + pack + PRE-SWIZZLED device-scope publish ----
    unsigned* hbw = hbuf + (size_t)(c*2 + pb)*NB*512;
#pragma unroll
    for (int mh = 0; mh < 2; ++mh) {
#pragma unroll
      for (int nt = 0; nt < 2; ++nt) {
        const int dcol = g*64 + wv*16 + nt*8 + (ln >> 1);
        const int ck = dcol >> 2, e = dcol & 3;
#pragma unroll
        for (int rg = 0; rg < 4; ++rg) {
          float av = acc[mh][nt][rg];
          float e0 = __expf(2.f * av);
          float hv = 1.f - 2.f * __builtin_amdgcn_rcpf(e0 + 1.f);
          unsigned u = (unsigned)__builtin_bit_cast(unsigned short, (f16)hv);
          unsigned o = (unsigned)__shfl_xor((int)u, 1);
          unsigned pk = (ln & 1) ? (o | (u << 16)) : (u | (o << 16));
          if (((rg ^ ln) & 1) == 0) {
            int b = mh*16 + q*4 + rg;
            int sd = ((ck ^ (b & 7)) << 2) | e;
            __hip_atomic_store(&hbw[b*512 + sd], pk, __ATOMIC_RELAXED, __HIP_MEMORY_SCOPE_AGENT);
          }
        }
      }
    }

    // ---- D: drain publishes + announce-early ----
    asm volatile("s_waitcnt vmcnt(0)" ::: "memory");
    if (lane == 0)
      __hip_atomic_store(&sent[((c*2 + pb)*NG + g)*4 + wv], s + 1,
                         __ATOMIC_RELAXED, __HIP_MEMORY_SCOPE_AGENT);

    // ---- E: xp-next loads ----
    f16x8 xn0 = (f16x8){}, xn1 = (f16x8){};
    if (s + 1 < L) {
      xn0 = xpv[(size_t)(t+1)*4096 + xpu];
      xn1 = xpv[(size_t)(t+1)*4096 + xpu + 64];
    }

    // ---- F: readout y(t-1) -> Ys[cur] (each wave reads ONE half of h(s-1)) ----
    const bool do_ro = (s > warm);
    if (do_ro) {
      const f16* fb = (wv < 2) ? (const f16*)&Hs0[rb][0][0] : (const f16*)&Hs1[0][0];
      const int kb = (wv & 1) * 8;  // ktl base within half
      f32x4 y0 = {0,0,0,0}, y1 = {0,0,0,0};
#pragma unroll
      for (int j = 0; j < 8; ++j) {
        const int co = (((kb + j)*4 + q) ^ sw) * 8;
        f16x8 h0 = *(const f16x8*)(fb + ln*512 + co);
        f16x8 h1 = *(const f16x8*)(fb + (16 + ln)*512 + co);
        y0 = MFMA16(h0, wO[j], y0);
        y1 = MFMA16(h1, wO[j], y1);
      }
#pragma unroll
      for (int rg = 0; rg < 4; ++rg) {
        Ys[cur][wv][q*4 + rg][ln]      = y0[rg];
        Ys[cur][wv][16 + q*4 + rg][ln] = y1[rg];
      }
    }

    // ---- G: poll own-half sentinels (post-readout; proven placement) ----
    if (lane < 16) {
      const int* sp = spl + pb*NG*4;
      long long dl = clock64() + 10000000LL;  // watchdog ~4 ms
      int spin = 0;
      while (__hip_atomic_load(sp, __ATOMIC_RELAXED, __HIP_MEMORY_SCOPE_AGENT) < s + 1) {
        if (((++spin) & 15) == 0 && clock64() > dl) break;
      }
    }

    // ---- H: issue gathers (own half) ----
    {
      const u32x4* src = (const u32x4*)hbw;
#pragma unroll
      for (int j = 0; j < 16; ++j) {
        const u32x4* p = src + tid + j*256;
        asm volatile("global_load_dwordx4 %0, %1, off sc0 sc1"
                     : "=&v"(gbuf[j]) : "v"(p) : "memory");
      }
    }

    // ---- J (no bar1): even staged-write half0 h(s) -> Hs0[cur]; odd combine y(t-2)
    if (!odd) {
      u32x4* dst0 = (u32x4*)&Hs0[cur][0][0];
      asm volatile("s_waitcnt vmcnt(8)" ::: "memory");
      __builtin_amdgcn_sched_barrier(0);
#pragma unroll
      for (int j = 0; j < 8; ++j) dst0[(2*j + wr0)*64 + wcl] = gbuf[j];
      asm volatile("s_waitcnt vmcnt(0)" ::: "memory");
      __builtin_amdgcn_sched_barrier(0);
#pragma unroll
      for (int j = 8; j < 16; ++j) dst0[(2*j + wr0)*64 + wcl] = gbuf[j];
    } else if (s > warm + 1) {
      y_combine(rb, t - 2);   // F(s-1) partials, ordered by bar2(s-1)
    }

    xc0 = xn0; xc1 = xn1;
    __syncthreads();  // bar2: Hs0[cur] + Ys[cur] ready for step s+1
  }

  // ---- epilogue ----
  // odd: finish half1 of h(L-1); even: combine pending y(t0+L-2)
  if (odd) {
    asm volatile("s_waitcnt vmcnt(0)" ::: "memory");
    __builtin_amdgcn_sched_barrier(0);
#pragma unroll
    for (int j = 0; j < 16; ++j) dst1[(2*j + wr0)*64 + wcl] = gbuf[j];
  } else {
    y_combine((L - 1) & 1, t0 + L - 2);
  }
  __syncthreads();
  // final readout of h(L-1): half0 in Hs0[(L-1)&1], half1 in Hs1
  {
    const int rbF = (L - 1) & 1;
    const f16* fb = (wv < 2) ? (const f16*)&Hs0[rbF][0][0] : (const f16*)&Hs1[0][0];
    const int kb = (wv & 1) * 8;
    f32x4 y0 = {0,0,0,0}, y1 = {0,0,0,0};
#pragma unroll
    for (int j = 0; j < 8; ++j) {
      const int co = (((kb + j)*4 + q) ^ sw) * 8;
      f16x8 h0 = *(const f16x8*)(fb + ln*512 + co);
      f16x8 h1 = *(const f16x8*)(fb + (16 + ln)*512 + co);
      y0 = MFMA16(h0, wO[j], y0);
      y1 = MFMA16(h1, wO[j], y1);
    }
#pragma unroll
    for (int rg = 0; rg < 4; ++rg) {
      Ys[L & 1][wv][q*4 + rg][ln]      = y0[rg];
      Ys[L & 1][wv][16 + q*4 + rg][ln] = y1[rg];
    }
    __syncthreads();
    if (odd) y_combine(L & 1, t0 + L - 1);
  }
}

extern "C" void kernel_launch(void* const* d_in, const int* in_sizes, int n_in,
                              void* d_out, int out_size, void* d_ws, size_t ws_size,
                              hipStream_t stream) {
  (void)in_sizes; (void)n_in; (void)out_size; (void)ws_size;
  const float* x   = (const float*)d_in[0];
  const float* Win = (const float*)d_in[1];
  const float* W   = (const float*)d_in[2];
  const float* Wow = (const float*)d_in[3];
  const float* Wob = (const float*)d_in[4];
  float* out = (float*)d_out;

  // workspace layout (~70.3 MB total)
  f16*      xpw  = (f16*)d_ws;                                   // 64 MiB
  unsigned* hbuf = (unsigned*)((char*)d_ws + 67108864);          // 4 MiB
  f16*      Wh   = (f16*)((char*)d_ws + 71303168);               // 2 MiB
  f16*      Woh  = (f16*)((char*)d_ws + 73400320);               // 256 KiB
  int*      sent = (int*)((char*)d_ws + 73662464);               // 8 KiB

  hipMemsetAsync(sent, 0, NC*2*NG*4*sizeof(int), stream);

  xp_kernel<<<dim3(NS/4), dim3(256), 0, stream>>>(x, Win, xpw, W, Wow, Wh, Woh);
  esn_kernel<<<dim3(NC*NG), dim3(256), 0, stream>>>(Wh, Woh, Wob, out, xpw, hbuf, sent);
}